// Round 2
// baseline (1039.233 us; speedup 1.0000x reference)
//
#include <hip/hip_runtime.h>
#include <hip/hip_bf16.h>
#include <stdint.h>

typedef unsigned short u16;
typedef __attribute__((ext_vector_type(8))) short bf16x8;   // 8 bf16 in 4 VGPRs
typedef __attribute__((ext_vector_type(4))) float f32x4;
typedef __attribute__((ext_vector_type(4))) unsigned short us4;

#define T_TOK   23328      // 32*729 tokens
#define MPAD    23424      // 183*128 (padded M for 128-tiles)
#define DMODEL  1152
#define N3      3456
#define NHEAD   16
#define HDIM    72
#define SEQ     729
#define VSTR    736        // vT row stride (729 padded; 736*2B = 16B-aligned rows)
#define SCALE_F 0.1178511301977579f   // 72^-0.5, folded into q at QKV epilogue

__device__ __forceinline__ u16 f2bf(float f) {
  unsigned u = __builtin_bit_cast(unsigned, f);
  u += 0x7fffu + ((u >> 16) & 1u);   // RNE
  return (u16)(u >> 16);
}

__device__ __forceinline__ f32x4 mfma16(bf16x8 a, bf16x8 b, f32x4 c) {
  return __builtin_amdgcn_mfma_f32_16x16x32_bf16(a, b, c, 0, 0, 0);
}

// async global->LDS, 16B per lane; lds ptr must be wave-uniform (computed from wave id only)
#define GL16(g, l)                                                        \
  __builtin_amdgcn_global_load_lds(                                       \
      (const __attribute__((address_space(1))) void*)(g),                 \
      (__attribute__((address_space(3))) void*)(l), 16, 0, 0)

// ---------------- conversion kernels ----------------

// hidden fp32 [T][D] -> bf16 [MPAD][D], zero pad rows (pad rows stay 0 for out-GEMM A reads)
__global__ void k_cvt_hidden(const float* __restrict__ in, u16* __restrict__ out) {
  size_t i4 = ((size_t)blockIdx.x * blockDim.x + threadIdx.x) * 4;
  if (i4 >= (size_t)MPAD * DMODEL) return;
  us4 o;
  if (i4 < (size_t)T_TOK * DMODEL) {
    float4 v = *(const float4*)(in + i4);
    o[0] = f2bf(v.x); o[1] = f2bf(v.y); o[2] = f2bf(v.z); o[3] = f2bf(v.w);
  } else {
    o[0] = 0; o[1] = 0; o[2] = 0; o[3] = 0;
  }
  *(us4*)(out + i4) = o;
}

// w [R][C] fp32 -> wt [C][R] bf16  (B^T form for the GEMMs)
template <int R, int C>
__global__ void k_transpose(const float* __restrict__ w, u16* __restrict__ wt) {
  size_t i = (size_t)blockIdx.x * blockDim.x + threadIdx.x;
  if (i >= (size_t)R * C) return;
  int n  = (int)(i / R);
  int kk = (int)(i - (size_t)n * R);
  wt[i] = f2bf(w[(size_t)kk * C + n]);
}

// ---------------- GEMM (m97 structure: 128x128 tile, BK=32, 4 waves) ----------------
// C[m][n] = sum_k A[m][k] * Bt[n][k] + bias[n]
// EPI=0: scatter to q (scaled), k, vT(head-transposed). EPI=1: fp32 out + bias.
template <int EPI>
__global__ __launch_bounds__(256) void k_gemm(
    const u16* __restrict__ A, const u16* __restrict__ Bt,
    const float* __restrict__ bias,
    u16* __restrict__ qo, u16* __restrict__ ko, u16* __restrict__ vTo,
    float* __restrict__ outp)
{
  __shared__ u16 As[128 * 32];
  __shared__ u16 Bs[128 * 32];
  const int tid  = threadIdx.x;
  const int wave = tid >> 6;
  const int lane = tid & 63;
  const int m0 = blockIdx.y * 128;
  const int n0 = blockIdx.x * 128;
  const int wm = (wave >> 1) * 64;    // wave's 64x64 quadrant
  const int wn = (wave & 1) * 64;

  // staging map: LDS byte = r*4096 + wave*1024 + lane*16  <-> row = 64r+16w+(lane>>2), colB = (lane&3)*16
  const int rofs = wave * 16 + (lane >> 2);
  const int cofs = (lane & 3) * 8;            // element offset within row
  const u16* gA0 = A  + (size_t)(m0 + rofs) * DMODEL + cofs;
  const u16* gA1 = gA0 + (size_t)64 * DMODEL;
  const u16* gB0 = Bt + (size_t)(n0 + rofs) * DMODEL + cofs;
  const u16* gB1 = gB0 + (size_t)64 * DMODEL;
  char* lA0 = (char*)As + wave * 1024;
  char* lA1 = (char*)As + 4096 + wave * 1024;
  char* lB0 = (char*)Bs + wave * 1024;
  char* lB1 = (char*)Bs + 4096 + wave * 1024;

  const int fr = lane & 15;           // fragment row/col within 16
  const int fk = (lane >> 4) * 8;     // fragment K offset

  f32x4 acc[4][4] = {};

  for (int kt = 0; kt < DMODEL; kt += 32) {
    GL16(gA0 + kt, lA0);
    GL16(gA1 + kt, lA1);
    GL16(gB0 + kt, lB0);
    GL16(gB1 + kt, lB1);
    __syncthreads();                  // drains vmcnt -> staged data visible
    bf16x8 af[4], bfrag[4];
#pragma unroll
    for (int i = 0; i < 4; ++i)
      af[i] = *(const bf16x8*)&As[(wm + i * 16 + fr) * 32 + fk];
#pragma unroll
    for (int j = 0; j < 4; ++j)
      bfrag[j] = *(const bf16x8*)&Bs[(wn + j * 16 + fr) * 32 + fk];
#pragma unroll
    for (int i = 0; i < 4; ++i)
#pragma unroll
      for (int j = 0; j < 4; ++j)
        acc[i][j] = mfma16(af[i], bfrag[j], acc[i][j]);
    __syncthreads();                  // all reads done before next stage overwrites
  }

  // epilogue. C-frag layout: col = lane&15, row = (lane>>4)*4 + reg  [m89-verified]
#pragma unroll
  for (int j = 0; j < 4; ++j) {
    const int n = n0 + wn + j * 16 + fr;
    const float bi = bias[n];
    if (EPI == 0) {
      const int which = n / DMODEL;          // 0=q 1=k 2=v (block-uniform: 128 | 1152)
      const int rr = n - which * DMODEL;
      const int h = rr / HDIM;
      const int d = rr - h * HDIM;
#pragma unroll
      for (int i = 0; i < 4; ++i) {
        const int tr = m0 + wm + i * 16 + (lane >> 4) * 4;
#pragma unroll
        for (int rg = 0; rg < 4; ++rg) {
          const int t = tr + rg;
          if (t < T_TOK) {
            const int bb = t / SEQ;
            const int s  = t - bb * SEQ;
            const int bh = bb * NHEAD + h;
            const float val = acc[i][j][rg] + bi;
            if (which == 0)
              qo[((size_t)bh * SEQ + s) * HDIM + d] = f2bf(val * SCALE_F);
            else if (which == 1)
              ko[((size_t)bh * SEQ + s) * HDIM + d] = f2bf(val);
            else  // V stored head-transposed [bh][d][s] for contiguous PV B-frags
              vTo[((size_t)bh * HDIM + d) * VSTR + s] = f2bf(val);
          }
        }
      }
    } else {
#pragma unroll
      for (int i = 0; i < 4; ++i) {
        const int tr = m0 + wm + i * 16 + (lane >> 4) * 4;
#pragma unroll
        for (int rg = 0; rg < 4; ++rg) {
          const int t = tr + rg;
          if (t < T_TOK)
            outp[(size_t)t * DMODEL + n] = acc[i][j][rg] + bi;
        }
      }
    }
  }
}

// ---------------- flash attention: 1 wave per (bh, 16-row q-tile) ----------------
__global__ __launch_bounds__(64) void k_attn(
    const u16* __restrict__ q, const u16* __restrict__ k,
    const u16* __restrict__ vT, u16* __restrict__ aout)
{
  const int lane = threadIdx.x;
  const int qt = blockIdx.x;     // 0..45
  const int bh = blockIdx.y;     // 0..511
  const int q0 = qt * 16;
  const int fr = lane & 15;
  const int fg = lane >> 4;
  const int fk = fg * 8;

  const u16* qb = q  + (size_t)bh * (SEQ * HDIM);
  const u16* kb = k  + (size_t)bh * (SEQ * HDIM);
  const u16* vb = vT + (size_t)bh * (HDIM * VSTR);

  __shared__ u16 pl[16][40];     // P tile 16x32 bf16, rows padded to 80B (16B-aligned, 2-way banks)

  // Q fragments (hd=72 = 32+32+8; chunk2 valid only for lanes with fk==0)
  const int qrow = q0 + fr;
  const bool qv = qrow < SEQ;
  bf16x8 qf0 = {}, qf1 = {}, qf2 = {};
  if (qv) {
    const u16* qp = qb + (size_t)qrow * HDIM;
    qf0 = *(const bf16x8*)(qp + fk);
    qf1 = *(const bf16x8*)(qp + 32 + fk);
    if (fg == 0) qf2 = *(const bf16x8*)(qp + 64);
  }

  f32x4 oacc[5] = {};            // 5 d-tiles of 16 (72 -> 80), C layout
  float mrun[4] = {-1e30f, -1e30f, -1e30f, -1e30f};
  float lrun[4] = {0.f, 0.f, 0.f, 0.f};

  for (int kt = 0; kt < SEQ; kt += 32) {
    f32x4 sc[2];
#pragma unroll
    for (int hh = 0; hh < 2; ++hh) {
      const int krow = kt + hh * 16 + fr;
      bf16x8 kf0 = {}, kf1 = {}, kf2 = {};
      if (krow < SEQ) {
        const u16* kp = kb + (size_t)krow * HDIM;
        kf0 = *(const bf16x8*)(kp + fk);
        kf1 = *(const bf16x8*)(kp + 32 + fk);
        if (fg == 0) kf2 = *(const bf16x8*)(kp + 64);
      }
      f32x4 z = {};
      z = mfma16(qf0, kf0, z);
      z = mfma16(qf1, kf1, z);
      z = mfma16(qf2, kf2, z);
      if (krow >= SEQ) { z[0] = -1e30f; z[1] = -1e30f; z[2] = -1e30f; z[3] = -1e30f; }
      sc[hh] = z;
    }
    // online softmax; row r of this tile = fg*4+r, its 32 cols live across the 16-lane group
#pragma unroll
    for (int r = 0; r < 4; ++r) {
      float mx = fmaxf(sc[0][r], sc[1][r]);
      mx = fmaxf(mx, __shfl_xor(mx, 1));
      mx = fmaxf(mx, __shfl_xor(mx, 2));
      mx = fmaxf(mx, __shfl_xor(mx, 4));
      mx = fmaxf(mx, __shfl_xor(mx, 8));
      const float mnew = fmaxf(mrun[r], mx);
      const float resc = __expf(mrun[r] - mnew);   // first iter: exp(-1e30)=0
      mrun[r] = mnew;
      const float p0 = __expf(sc[0][r] - mnew);
      const float p1 = __expf(sc[1][r] - mnew);
      float ps = p0 + p1;
      ps += __shfl_xor(ps, 1);
      ps += __shfl_xor(ps, 2);
      ps += __shfl_xor(ps, 4);
      ps += __shfl_xor(ps, 8);
      lrun[r] = lrun[r] * resc + ps;
#pragma unroll
      for (int v = 0; v < 5; ++v) oacc[v][r] *= resc;
      pl[fg * 4 + r][fr]      = f2bf(p0);
      pl[fg * 4 + r][16 + fr] = f2bf(p1);
    }
    __syncthreads();
    // P as A-frag: row=lane&15, k = fg*8..+8
    const bf16x8 pa = *(const bf16x8*)&pl[fr][fk];
#pragma unroll
    for (int v = 0; v < 5; ++v) {
      const int d = v * 16 + fr;
      bf16x8 vf = {};
      if (d < HDIM)   // B-frag: n=d (lane&15), k=key (contiguous in vT row); OOB keys have P=0
        vf = *(const bf16x8*)(vb + (size_t)d * VSTR + kt + fk);
      oacc[v] = mfma16(pa, vf, oacc[v]);
    }
    __syncthreads();
  }

  const int bb = bh >> 4, h = bh & 15;
#pragma unroll
  for (int r = 0; r < 4; ++r) {
    const int row = q0 + fg * 4 + r;
    if (row < SEQ) {
      const float inv = 1.0f / lrun[r];
      u16* op = aout + (size_t)(bb * SEQ + row) * DMODEL + h * HDIM;
#pragma unroll
      for (int v = 0; v < 5; ++v) {
        const int d = v * 16 + fr;
        if (d < HDIM) op[d] = f2bf(oacc[v][r] * inv);
      }
    }
  }
}

// ---------------- launch ----------------
extern "C" void kernel_launch(void* const* d_in, const int* in_sizes, int n_in,
                              void* d_out, int out_size, void* d_ws, size_t ws_size,
                              hipStream_t stream) {
  (void)in_sizes; (void)n_in; (void)out_size; (void)ws_size;
  const float* hs   = (const float*)d_in[0];
  const float* wqkv = (const float*)d_in[1];
  const float* bqkv = (const float*)d_in[2];
  const float* wout = (const float*)d_in[3];
  const float* bout = (const float*)d_in[4];
  float* out = (float*)d_out;

  // workspace layout (all 16B aligned); total ~226 MB
  u16* hbuf  = (u16*)d_ws;                        // [MPAD][1152] bf16: hidden, later reused as attn_out
  u16* wqkvT = hbuf  + (size_t)MPAD * DMODEL;     // [3456][1152]
  u16* woutT = wqkvT + (size_t)N3 * DMODEL;       // [1152][1152]
  u16* qb    = woutT + (size_t)DMODEL * DMODEL;   // [512][729][72]
  u16* kb    = qb    + (size_t)512 * SEQ * HDIM;  // [512][729][72]
  u16* vTb   = kb    + (size_t)512 * SEQ * HDIM;  // [512][72][736]

  k_cvt_hidden<<<(MPAD * DMODEL / 4 + 255) / 256, 256, 0, stream>>>(hs, hbuf);
  k_transpose<DMODEL, N3><<<((size_t)DMODEL * N3 + 255) / 256, 256, 0, stream>>>(wqkv, wqkvT);
  k_transpose<DMODEL, DMODEL><<<((size_t)DMODEL * DMODEL + 255) / 256, 256, 0, stream>>>(wout, woutT);
  k_gemm<0><<<dim3(N3 / 128, MPAD / 128), 256, 0, stream>>>(hbuf, wqkvT, bqkv, qb, kb, vTb, nullptr);
  k_attn<<<dim3(46, 512), 64, 0, stream>>>(qb, kb, vTb, hbuf);
  k_gemm<1><<<dim3(DMODEL / 128, MPAD / 128), 256, 0, stream>>>(hbuf, woutT, bout,
                                                                nullptr, nullptr, nullptr, out);
}

// Round 5
// 882.916 us; speedup vs baseline: 1.1770x; 1.1770x over previous
//
#include <hip/hip_runtime.h>
#include <hip/hip_bf16.h>
#include <stdint.h>

typedef unsigned short u16;
typedef __attribute__((ext_vector_type(8))) short bf16x8;   // 8 bf16 in 4 VGPRs
typedef __attribute__((ext_vector_type(4))) float f32x4;
typedef __attribute__((ext_vector_type(4))) unsigned short us4;

#define T_TOK   23328      // 32*729 tokens
#define MPAD    23424      // 183*128 (padded M for 128-tiles)
#define DMODEL  1152
#define N3      3456
#define NHEAD   16
#define HDIM    72
#define SEQ     729
#define VSTR    736        // vT row stride (729 padded; 736*2B = 16B-aligned rows)
#define SCALE_F 0.1178511301977579f   // 72^-0.5, folded into q at QKV epilogue
#define KVB     64
#define NT      12         // ceil(729/64)
#define THR     8.0f       // defer-max threshold (natural-log domain, P <= e^8)

__device__ __forceinline__ u16 f2bf(float f) {
  unsigned u = __builtin_bit_cast(unsigned, f);
  u += 0x7fffu + ((u >> 16) & 1u);   // RNE
  return (u16)(u >> 16);
}

__device__ __forceinline__ f32x4 mfma16(bf16x8 a, bf16x8 b, f32x4 c) {
  return __builtin_amdgcn_mfma_f32_16x16x32_bf16(a, b, c, 0, 0, 0);
}

// async global->LDS, 16B per lane; lds ptr must be wave-uniform (computed from wave id only)
#define GL16(g, l)                                                        \
  __builtin_amdgcn_global_load_lds(                                       \
      (const __attribute__((address_space(1))) void*)(g),                 \
      (__attribute__((address_space(3))) void*)(l), 16, 0, 0)

// ---------------- conversion kernels ----------------

__global__ void k_cvt_hidden(const float* __restrict__ in, u16* __restrict__ out) {
  size_t i4 = ((size_t)blockIdx.x * blockDim.x + threadIdx.x) * 4;
  if (i4 >= (size_t)MPAD * DMODEL) return;
  us4 o;
  if (i4 < (size_t)T_TOK * DMODEL) {
    float4 v = *(const float4*)(in + i4);
    o[0] = f2bf(v.x); o[1] = f2bf(v.y); o[2] = f2bf(v.z); o[3] = f2bf(v.w);
  } else {
    o[0] = 0; o[1] = 0; o[2] = 0; o[3] = 0;
  }
  *(us4*)(out + i4) = o;
}

template <int R, int C>
__global__ void k_transpose(const float* __restrict__ w, u16* __restrict__ wt) {
  size_t i = (size_t)blockIdx.x * blockDim.x + threadIdx.x;
  if (i >= (size_t)R * C) return;
  int n  = (int)(i / R);
  int kk = (int)(i - (size_t)n * R);
  wt[i] = f2bf(w[(size_t)kk * C + n]);
}

// ---------------- GEMM (m97 structure: 128x128 tile, BK=32, 4 waves) — unchanged ----------------
template <int EPI>
__global__ __launch_bounds__(256) void k_gemm(
    const u16* __restrict__ A, const u16* __restrict__ Bt,
    const float* __restrict__ bias,
    u16* __restrict__ qo, u16* __restrict__ ko, u16* __restrict__ vTo,
    float* __restrict__ outp)
{
  __shared__ u16 As[128 * 32];
  __shared__ u16 Bs[128 * 32];
  const int tid  = threadIdx.x;
  const int wave = tid >> 6;
  const int lane = tid & 63;
  const int m0 = blockIdx.y * 128;
  const int n0 = blockIdx.x * 128;
  const int wm = (wave >> 1) * 64;
  const int wn = (wave & 1) * 64;

  const int rofs = wave * 16 + (lane >> 2);
  const int cofs = (lane & 3) * 8;
  const u16* gA0 = A  + (size_t)(m0 + rofs) * DMODEL + cofs;
  const u16* gA1 = gA0 + (size_t)64 * DMODEL;
  const u16* gB0 = Bt + (size_t)(n0 + rofs) * DMODEL + cofs;
  const u16* gB1 = gB0 + (size_t)64 * DMODEL;
  char* lA0 = (char*)As + wave * 1024;
  char* lA1 = (char*)As + 4096 + wave * 1024;
  char* lB0 = (char*)Bs + wave * 1024;
  char* lB1 = (char*)Bs + 4096 + wave * 1024;

  const int fr = lane & 15;
  const int fk = (lane >> 4) * 8;

  f32x4 acc[4][4] = {};

  for (int kt = 0; kt < DMODEL; kt += 32) {
    GL16(gA0 + kt, lA0);
    GL16(gA1 + kt, lA1);
    GL16(gB0 + kt, lB0);
    GL16(gB1 + kt, lB1);
    __syncthreads();
    bf16x8 af[4], bfrag[4];
#pragma unroll
    for (int i = 0; i < 4; ++i)
      af[i] = *(const bf16x8*)&As[(wm + i * 16 + fr) * 32 + fk];
#pragma unroll
    for (int j = 0; j < 4; ++j)
      bfrag[j] = *(const bf16x8*)&Bs[(wn + j * 16 + fr) * 32 + fk];
#pragma unroll
    for (int i = 0; i < 4; ++i)
#pragma unroll
      for (int j = 0; j < 4; ++j)
        acc[i][j] = mfma16(af[i], bfrag[j], acc[i][j]);
    __syncthreads();
  }

#pragma unroll
  for (int j = 0; j < 4; ++j) {
    const int n = n0 + wn + j * 16 + fr;
    const float bi = bias[n];
    if (EPI == 0) {
      const int which = n / DMODEL;
      const int rr = n - which * DMODEL;
      const int h = rr / HDIM;
      const int d = rr - h * HDIM;
#pragma unroll
      for (int i = 0; i < 4; ++i) {
        const int tr = m0 + wm + i * 16 + (lane >> 4) * 4;
#pragma unroll
        for (int rg = 0; rg < 4; ++rg) {
          const int t = tr + rg;
          if (t < T_TOK) {
            const int bb = t / SEQ;
            const int s  = t - bb * SEQ;
            const int bh = bb * NHEAD + h;
            const float val = acc[i][j][rg] + bi;
            if (which == 0)
              qo[((size_t)bh * SEQ + s) * HDIM + d] = f2bf(val * SCALE_F);
            else if (which == 1)
              ko[((size_t)bh * SEQ + s) * HDIM + d] = f2bf(val);
            else
              vTo[((size_t)bh * HDIM + d) * VSTR + s] = f2bf(val);
          }
        }
      }
    } else {
#pragma unroll
      for (int i = 0; i < 4; ++i) {
        const int tr = m0 + wm + i * 16 + (lane >> 4) * 4;
#pragma unroll
        for (int rg = 0; rg < 4; ++rg) {
          const int t = tr + rg;
          if (t < T_TOK)
            outp[(size_t)t * DMODEL + n] = acc[i][j][rg] + bi;
        }
      }
    }
  }
}

// ---------------- flash attention v2.1: 4 waves/block, 64 q-rows, KVB=64 LDS-staged ----------------
// v2.1 fix: zero the Ks pad (elements 4608..4639) — the unconditional kf2 load reads it for
// K-row 63 / fg>=1, and uninit LDS bits can form bf16 NaN/Inf; MFMA's 0*NaN = NaN. [round-4 bug]

// stage one 64-key K tile (64x72, 144B rows, 576 chunks) + V tile (72x64, swizzled, 576 chunks)
__device__ __forceinline__ void stage_kv(const u16* __restrict__ kb, const u16* __restrict__ vb,
                                         u16* KsB, u16* VsB, int kt, int wv, int lane) {
#pragma unroll
  for (int rdi = 0; rdi < 2; ++rdi) {
    const int c0 = rdi * 256 + wv * 64;       // wave-uniform chunk base
    {
      const int c = c0 + lane;
      const int row = c / 9;                  // 144B rows = 9 chunks
      const int off = (c - row * 9) * 8;
      GL16(kb + (size_t)(kt + row) * HDIM + off, KsB + (size_t)c0 * 8);
    }
    {
      const int c = c0 + lane;
      const int d = c >> 3;                   // 128B rows = 8 chunks
      int off = kt + (((c & 7) ^ (d & 7)) << 3);   // pre-swizzled source (rule 21)
      off = off > (VSTR - 8) ? (VSTR - 8) : off;   // clamp: keys>=729 are masked anyway
      GL16(vb + (size_t)d * VSTR + off, VsB + (size_t)c0 * 8);
    }
  }
  if (wv == 0) {                              // chunks 512..575
    const int c = 512 + lane;
    const int row = c / 9;
    const int off = (c - row * 9) * 8;
    GL16(kb + (size_t)(kt + row) * HDIM + off, KsB + (size_t)512 * 8);
    const int d = c >> 3;
    int voff = kt + (((c & 7) ^ (d & 7)) << 3);
    voff = voff > (VSTR - 8) ? (VSTR - 8) : voff;
    GL16(vb + (size_t)d * VSTR + voff, VsB + (size_t)512 * 8);
  }
}

__global__ __launch_bounds__(256) void k_attn(
    const u16* __restrict__ q, const u16* __restrict__ k,
    const u16* __restrict__ vT, u16* __restrict__ aout)
{
  // Ks: 64x72 + 32-elem pad (kf2 over-read spill stays in-array; pad zeroed at init)
  // Vs: 80x64 (rows 72..79: row72 = 1.0 ones-column, 73..79 zeroed)
  __shared__ alignas(16) u16 Ks[2][4640];
  __shared__ alignas(16) u16 Vs[2][5120];
  __shared__ alignas(16) u16 pl[4][16][72];   // per-wave P tile, 144B pitch

  const int tid  = threadIdx.x;
  const int wv   = tid >> 6;
  const int lane = tid & 63;
  const int fr = lane & 15;
  const int fg = lane >> 4;
  const int fk = fg * 8;

  const int bh = blockIdx.y;
  const int qbase = blockIdx.x * 64 + wv * 16;

  const u16* qb = q  + (size_t)bh * (SEQ * HDIM);
  const u16* kb = k  + (size_t)bh * (SEQ * HDIM);
  const u16* vb = vT + (size_t)bh * (HDIM * VSTR);

  // one-time LDS init (staging never touches these regions):
  //  - V ones-column row 72 (denominator trick) + zero rows 73..79
  //  - Ks 32-elem pad x2 buffers (kf2 over-read target) — MUST be zero, not uninit
  if (tid < 64) { Vs[0][4608 + tid] = 0x3F80; Vs[1][4608 + tid] = 0x3F80; }
  for (int i = tid; i < 448; i += 256) { Vs[0][4672 + i] = 0; Vs[1][4672 + i] = 0; }
  if (tid < 32) { Ks[0][4608 + tid] = 0; Ks[1][4608 + tid] = 0; }

  // Q fragments (hd=72 = 32+32+8); qf2 nonzero only for fg==0 (k-slots 72..95 are zero)
  const int qrow = qbase + fr;
  bf16x8 qf0 = {}, qf1 = {}, qf2 = {};
  if (qrow < SEQ) {
    const u16* qp = qb + (size_t)qrow * HDIM;
    qf0 = *(const bf16x8*)(qp + fk);
    qf1 = *(const bf16x8*)(qp + 32 + fk);
    if (fg == 0) qf2 = *(const bf16x8*)(qp + 64);
  }

  f32x4 oacc[5] = {};                   // d-tiles 0..3: output; 4: d=64..71 + l at fr==8
  float mrun[4] = {-1e30f, -1e30f, -1e30f, -1e30f};

  stage_kv(kb, vb, Ks[0], Vs[0], 0, wv, lane);
  __syncthreads();

  int buf = 0;
  for (int t = 0; t < NT; ++t) {
    const int kt = t * KVB;
    if (t + 1 < NT)
      stage_kv(kb, vb, Ks[buf ^ 1], Vs[buf ^ 1], kt + KVB, wv, lane);

    // ---- QK^T: 4 halves of 16 keys ----
    const char* kB = (const char*)Ks[buf];
    f32x4 sc[4];
#pragma unroll
    for (int hh = 0; hh < 4; ++hh) {
      const char* krow = kB + (hh * 16 + fr) * 144;
      bf16x8 kf0 = *(const bf16x8*)(krow + fg * 16);
      bf16x8 kf1 = *(const bf16x8*)(krow + 64 + fg * 16);
      bf16x8 kf2 = *(const bf16x8*)(krow + 128 + fg * 16);  // fg>0: next-row data or zeroed pad; A-side is 0
      f32x4 z = {};
      z = mfma16(qf0, kf0, z);
      z = mfma16(qf1, kf1, z);
      z = mfma16(qf2, kf2, z);
      sc[hh] = z;
    }
    if (kt + KVB > SEQ) {               // tail tile: mask invalid keys (col = fr)
#pragma unroll
      for (int hh = 0; hh < 4; ++hh)
        if (kt + hh * 16 + fr >= SEQ) {
          sc[hh][0] = -1e30f; sc[hh][1] = -1e30f; sc[hh][2] = -1e30f; sc[hh][3] = -1e30f;
        }
    }

    // ---- online softmax, defer-max ----
    float tmx[4];
    bool needs = false;
#pragma unroll
    for (int r = 0; r < 4; ++r) {
      tmx[r] = fmaxf(fmaxf(sc[0][r], sc[1][r]), fmaxf(sc[2][r], sc[3][r]));
      needs |= (tmx[r] > mrun[r] + THR);
    }
    if (__any(needs)) {                 // wave-uniform rescale path
#pragma unroll
      for (int r = 0; r < 4; ++r) {
        float tm = tmx[r];
        tm = fmaxf(tm, __shfl_xor(tm, 1));
        tm = fmaxf(tm, __shfl_xor(tm, 2));
        tm = fmaxf(tm, __shfl_xor(tm, 4));
        tm = fmaxf(tm, __shfl_xor(tm, 8));
        const float mnew = fmaxf(mrun[r], tm);
        const float resc = __expf(mrun[r] - mnew);
        mrun[r] = mnew;
#pragma unroll
        for (int v = 0; v < 5; ++v) oacc[v][r] *= resc;
      }
    }
#pragma unroll
    for (int r = 0; r < 4; ++r) {
      const int prow = fg * 4 + r;      // C-frag row = q-row within wave tile
#pragma unroll
      for (int hh = 0; hh < 4; ++hh)
        pl[wv][prow][hh * 16 + fr] = f2bf(__expf(sc[hh][r] - mrun[r]));
    }

    // ---- PV: P[16x64] x V[64x80] (d=72 col of V = 1.0 -> l) ----
    const bf16x8 pa0 = *(const bf16x8*)&pl[wv][fr][fk];        // keys 0..31
    const bf16x8 pa1 = *(const bf16x8*)&pl[wv][fr][32 + fk];   // keys 32..63
    const char* vB = (const char*)Vs[buf];
    const int swz = (fr & 7) << 4;
#pragma unroll
    for (int v = 0; v < 5; ++v) {
      const char* vrow = vB + (size_t)(v * 16 + fr) * 128;
      bf16x8 vf0 = *(const bf16x8*)(vrow + ((fg * 16) ^ swz));
      bf16x8 vf1 = *(const bf16x8*)(vrow + (((4 + fg) * 16) ^ swz));
      oacc[v] = mfma16(pa0, vf0, oacc[v]);
      oacc[v] = mfma16(pa1, vf1, oacc[v]);
    }

    __syncthreads();                    // next tile staged + all waves done with buf
    buf ^= 1;
  }

  // ---- epilogue: l lives in oacc[4][r] at lane fr==8 of each fg group ----
  const int bb = bh >> 4, h = bh & 15;
#pragma unroll
  for (int r = 0; r < 4; ++r) {
    const int row = qbase + fg * 4 + r;
    if (row < SEQ) {
      const float l = __shfl(oacc[4][r], (lane & 48) | 8);
      const float inv = 1.0f / l;
      u16* op = aout + (size_t)(bb * SEQ + row) * DMODEL + h * HDIM;
#pragma unroll
      for (int v = 0; v < 5; ++v) {
        const int d = v * 16 + fr;
        if (d < HDIM) op[d] = f2bf(oacc[v][r] * inv);
      }
    }
  }
}

// ---------------- launch ----------------
extern "C" void kernel_launch(void* const* d_in, const int* in_sizes, int n_in,
                              void* d_out, int out_size, void* d_ws, size_t ws_size,
                              hipStream_t stream) {
  (void)in_sizes; (void)n_in; (void)out_size; (void)ws_size;
  const float* hs   = (const float*)d_in[0];
  const float* wqkv = (const float*)d_in[1];
  const float* bqkv = (const float*)d_in[2];
  const float* wout = (const float*)d_in[3];
  const float* bout = (const float*)d_in[4];
  float* out = (float*)d_out;

  u16* hbuf  = (u16*)d_ws;                        // [MPAD][1152] bf16: hidden, later attn_out
  u16* wqkvT = hbuf  + (size_t)MPAD * DMODEL;     // [3456][1152]
  u16* woutT = wqkvT + (size_t)N3 * DMODEL;       // [1152][1152]
  u16* qb    = woutT + (size_t)DMODEL * DMODEL;   // [512][729][72]
  u16* kb    = qb    + (size_t)512 * SEQ * HDIM;  // [512][729][72]
  u16* vTb   = kb    + (size_t)512 * SEQ * HDIM;  // [512][72][736]
  // note: attn K/V tail-tile staging reads up to 39 rows past a bh's K rows / clamped within
  // VSTR for V — always inside [kb, vTb end) -> in-bounds of d_ws, values masked by P=0.

  k_cvt_hidden<<<(MPAD * DMODEL / 4 + 255) / 256, 256, 0, stream>>>(hs, hbuf);
  k_transpose<DMODEL, N3><<<((size_t)DMODEL * N3 + 255) / 256, 256, 0, stream>>>(wqkv, wqkvT);
  k_transpose<DMODEL, DMODEL><<<((size_t)DMODEL * DMODEL + 255) / 256, 256, 0, stream>>>(wout, woutT);
  k_gemm<0><<<dim3(N3 / 128, MPAD / 128), 256, 0, stream>>>(hbuf, wqkvT, bqkv, qb, kb, vTb, nullptr);
  k_attn<<<dim3(12, 512), 256, 0, stream>>>(qb, kb, vTb, hbuf);
  k_gemm<1><<<dim3(DMODEL / 128, MPAD / 128), 256, 0, stream>>>(hbuf, woutT, bout,
                                                                nullptr, nullptr, nullptr, out);
}